// Round 12
// baseline (147.991 us; speedup 1.0000x reference)
//
#include <hip/hip_runtime.h>

// Hough voting (PoseCNN-style), round 12 — ZERO-GLOBAL-ATOMIC emit.
// label (B,H,W) i32; vertex (B,3C,H,W) f32; extents (C,3); meta (B,9);
// out (B,C,9) f32. B=2,C=22,H=480,W=640. Assumes H <= 512, C < 32.
//
// r12: r4..r11 floor at ~110us emit with no pipe >25% busy; six theories
// null. This round deletes ALL global-side serialization from emit:
//  - fixed 32KB record chunk per block (512px x 32 votes worst case, exact)
//    -> cursor atomics GONE; row-grouping via LDS scan; per-(block,row)
//    (offset<<16|count) published to a u32 table (coalesced).
//  - class cnt/zsum via PLAIN per-block partial stores + tree-reduce in
//    finalize -> 600-deep same-address atomic chains GONE.
//  - memset shrinks to keys only (352B); no CAP clamps needed.
// hist reads segments via the table (per-thread segment scan).

#define MAXC 32

__global__ __launch_bounds__(512) void emit_kernel(
    const int* __restrict__ label, const float* __restrict__ vertex,
    unsigned short* __restrict__ chunk, unsigned* __restrict__ table,
    unsigned* __restrict__ cntPart, float* __restrict__ zsumPart,
    int C, int H, int W, int HW, int GX)
{
    __shared__ unsigned s_bin[512];   // votes per destination row
    __shared__ unsigned s_pos[512];   // running write position per row
    __shared__ unsigned s_wtot[8];
    __shared__ unsigned s_ccnt[MAXC];
    __shared__ float s_cz[MAXC];

    int tid = threadIdx.x;
    int lane = tid & 63, wave = tid >> 6;
    int b = blockIdx.y, g = blockIdx.x;
    int p = g * 512 + tid;

    s_bin[tid] = 0u;
    if (tid < MAXC) { s_ccnt[tid] = 0u; s_cz[tid] = 0.0f; }
    __syncthreads();

    int lab = 0;
    bool fg = false;
    float nxn = 0.f, nyn = 0.f, xs = 0.f, ys = 0.f;
    if (p < HW) {
        lab = label[(size_t)b * HW + p];
        const float* vb = vertex + ((size_t)(b * 3 * C + 3 * lab)) * HW + p;
        float nx = vb[0];
        float ny = vb[(size_t)HW];
        float z  = vb[2 * (size_t)HW];
        atomicAdd(&s_ccnt[lab], 1u);
        atomicAdd(&s_cz[lab], z);
        if (lab > 0) {
            fg = true;
            // Match XLA f32 exactly: no FMA contraction, IEEE sqrt/div, RNE round.
            float nrm = __fsqrt_rn(__fadd_rn(__fmul_rn(nx, nx), __fmul_rn(ny, ny)));
            float inv = __fdiv_rn(1.0f, __fadd_rn(nrm, 1e-8f));
            nxn = __fmul_rn(nx, inv);
            nyn = __fmul_rn(ny, inv);
            xs = (float)(p % W);
            ys = (float)(p / W);
        }
    }

    // Pass A: count votes per destination row (scalars only).
    if (fg) {
        #pragma unroll
        for (int i = 1; i <= 32; ++i) {
            float t = (float)i * 4.0f;
            int px = (int)rintf(__fadd_rn(xs, __fmul_rn(nxn, t)));
            int py = (int)rintf(__fadd_rn(ys, __fmul_rn(nyn, t)));
            if (px >= 0 && px < W && py >= 0 && py < H)
                atomicAdd(&s_bin[py], 1u);
        }
    }
    __syncthreads();

    // Exclusive scan over 512 row bins (wave shuffle scan + cross-wave).
    unsigned own = s_bin[tid];
    unsigned v = own;
    #pragma unroll
    for (int off = 1; off < 64; off <<= 1) {
        unsigned u = __shfl_up(v, off, 64);
        if (lane >= off) v += u;
    }
    if (lane == 63) s_wtot[wave] = v;
    __syncthreads();
    if (tid == 0) {
        unsigned a = 0;
        #pragma unroll
        for (int w2 = 0; w2 < 8; ++w2) { unsigned t2 = s_wtot[w2]; s_wtot[w2] = a; a += t2; }
    }
    __syncthreads();
    unsigned base = v + s_wtot[wave] - own;   // exclusive base of row tid
    s_pos[tid] = base;
    // Publish (offset,count) for hist. base,count <= 16384 -> both fit 16 bits.
    table[((size_t)b * GX + g) * 512 + tid] = (base << 16) | own;
    __syncthreads();

    // Pass B: recompute votes (identical FP sequence) and write directly into
    // this block's fixed chunk, grouped by row. No bounds check needed: the
    // chunk holds the exact worst case (512 px x 32 votes).
    if (fg) {
        unsigned labsh = (unsigned)lab << 10;
        unsigned short* myChunk = chunk + (((size_t)b * GX + g) << 14);
        #pragma unroll
        for (int i = 1; i <= 32; ++i) {
            float t = (float)i * 4.0f;
            int px = (int)rintf(__fadd_rn(xs, __fmul_rn(nxn, t)));
            int py = (int)rintf(__fadd_rn(ys, __fmul_rn(nyn, t)));
            if (px >= 0 && px < W && py >= 0 && py < H) {
                unsigned slot = atomicAdd(&s_pos[py], 1u);
                myChunk[slot] = (unsigned short)(labsh | (unsigned)px);
            }
        }
    }

    // Class aggregates: PLAIN stores of per-block partials (no atomics).
    if (tid < C) {
        cntPart[((size_t)b * GX + g) * MAXC + tid] = s_ccnt[tid];
        zsumPart[((size_t)b * GX + g) * MAXC + tid] = s_cz[tid];
    }
}

__global__ __launch_bounds__(256) void hist_kernel(
    const unsigned short* __restrict__ chunk,
    const unsigned* __restrict__ table,
    unsigned long long* __restrict__ keys,
    int C, int H, int W, int GX)
{
    extern __shared__ char sm[];
    unsigned* hist = (unsigned*)sm;   // C*W/2 words, u16 pair per word
    unsigned long long* s_wb =
        (unsigned long long*)(sm + (size_t)(C * W / 2) * 4);  // C*4 wave bests

    int tid = threadIdx.x;
    int lane = tid & 63, wave = tid >> 6;
    int py = blockIdx.x;
    int b = blockIdx.y;
    int words = C * W / 2;

    for (int i = tid; i < words; i += 256) hist[i] = 0u;
    __syncthreads();

    // Each thread scans whole segments (one per emit-block) of this row.
    for (int g = tid; g < GX; g += 256) {
        unsigned e = table[((size_t)b * GX + g) * 512 + py];
        unsigned n = e & 0xFFFFu;
        if (!n) continue;
        const unsigned short* src = chunk + (((size_t)b * GX + g) << 14) + (e >> 16);
        for (unsigned i = 0; i < n; ++i) {
            unsigned r = src[i];
            unsigned idx = (r >> 10) * (unsigned)W + (r & 1023u);  // c*W+px
            atomicAdd(&hist[idx >> 1], 1u << ((idx & 1u) * 16));   // packed u16
        }
    }
    __syncthreads();

    // Per-class argmax over ALL cells of this row (zero counts included so
    // global tie-break == jnp.argmax: max count, then min flat index).
    unsigned rowbase = (unsigned)py * (unsigned)W;
    for (int c = 0; c < C; ++c) {
        unsigned long long best = 0;
        for (int px = tid; px < W; px += 256) {
            unsigned cv = (hist[(unsigned)(c * W + px) >> 1] >> ((px & 1) * 16)) & 0xFFFFu;
            unsigned long long k = ((unsigned long long)cv << 32)
                                 | (unsigned long long)(0xFFFFFFFFu - (rowbase + px));
            if (k > best) best = k;
        }
        #pragma unroll
        for (int off = 32; off > 0; off >>= 1) {
            unsigned long long o = __shfl_xor(best, off, 64);
            if (o > best) best = o;
        }
        if (lane == 0) s_wb[c * 4 + wave] = best;
    }
    __syncthreads();
    if (tid < C) {
        unsigned long long m = s_wb[tid * 4];
        #pragma unroll
        for (int w2 = 1; w2 < 4; ++w2)
            if (s_wb[tid * 4 + w2] > m) m = s_wb[tid * 4 + w2];
        atomicMax(&keys[b * C + tid], m);
    }
}

__global__ __launch_bounds__(512) void finalize_kernel(
    const unsigned long long* __restrict__ keys,
    const unsigned* __restrict__ cntPart,
    const float* __restrict__ zsumPart,
    const float* __restrict__ extents,
    const float* __restrict__ meta,
    float* __restrict__ out,
    int B, int C, int W, int GX)
{
    __shared__ float s_cnt[64];
    __shared__ float s_z[64];

    int tid = threadIdx.x;
    int lane = tid & 63, wave = tid >> 6;
    int P = B * C;

    // Tree-reduce per-block partials: wave w handles pairs w, w+8, ...
    for (int pair = wave; pair < P; pair += 8) {
        int b = pair / C, c = pair % C;
        unsigned cs = 0; float zs = 0.f;
        for (int g = lane; g < GX; g += 64) {
            size_t idx = ((size_t)b * GX + g) * MAXC + c;
            cs += cntPart[idx];
            zs += zsumPart[idx];
        }
        #pragma unroll
        for (int off = 32; off > 0; off >>= 1) {
            cs += __shfl_xor(cs, off, 64);
            zs += __shfl_xor(zs, off, 64);
        }
        if (lane == 0) { s_cnt[pair] = (float)cs; s_z[pair] = zs; }
    }
    __syncthreads();

    if (tid < P) {
        int b = tid / C, c = tid % C;
        unsigned long long k = keys[tid];
        unsigned votes = (unsigned)(k >> 32);
        unsigned peak = 0xFFFFFFFFu - (unsigned)(k & 0xFFFFFFFFull);
        float cx = (float)(peak % (unsigned)W);
        float cy = (float)(peak / (unsigned)W);
        float n = s_cnt[tid];
        float depth = s_z[tid] / fmaxf(n, 1.0f);
        float fx = meta[b * 9 + 0];
        const float* e = extents + c * 3;
        float diag = sqrtf(e[0] * e[0] + e[1] * e[1] + e[2] * e[2]);
        float half = 0.5f * diag * fx / fmaxf(fabsf(depth), 0.001f);
        float* o = out + (size_t)tid * 9;
        o[0] = (float)c;
        o[1] = (float)votes;
        o[2] = cx - half;
        o[3] = cy - half;
        o[4] = cx + half;
        o[5] = cy + half;
        o[6] = cx;
        o[7] = cy;
        o[8] = depth;
    }
}

extern "C" void kernel_launch(void* const* d_in, const int* in_sizes, int n_in,
                              void* d_out, int out_size, void* d_ws, size_t ws_size,
                              hipStream_t stream)
{
    const int* label    = (const int*)d_in[0];
    const float* vertex = (const float*)d_in[1];
    const float* extents= (const float*)d_in[2];
    const float* meta   = (const float*)d_in[3];
    // d_in[4] = gt (unused), d_in[5] = is_train (unused)

    int C = in_sizes[2] / 3;      // extents: C*3
    int B = in_sizes[3] / 9;      // meta: B*9
    int HW = in_sizes[0] / B;     // label: B*H*W
    const int W = 640;
    int H = HW / W;
    int GX = (HW + 511) / 512;    // emit blocks per batch

    // Workspace: keys (u64, memset) | cntPart | zsumPart | table | chunk
    size_t keysOff  = 0;
    size_t keysBytes= (size_t)B * C * 8;
    size_t cpOff    = (keysBytes + 63) & ~(size_t)63;
    size_t cpBytes  = (size_t)B * GX * MAXC * 4;
    size_t zpOff    = cpOff + cpBytes;
    size_t tabOff   = zpOff + cpBytes;
    size_t tabBytes = (size_t)B * GX * 512 * 4;
    size_t chOff    = (tabOff + tabBytes + 63) & ~(size_t)63;

    unsigned long long* keys = (unsigned long long*)((char*)d_ws + keysOff);
    unsigned* cntPart        = (unsigned*)((char*)d_ws + cpOff);
    float* zsumPart          = (float*)((char*)d_ws + zpOff);
    unsigned* table          = (unsigned*)((char*)d_ws + tabOff);
    unsigned short* chunk    = (unsigned short*)((char*)d_ws + chOff);

    hipMemsetAsync(d_ws, 0, keysBytes, stream);

    dim3 egrid(GX, B);
    emit_kernel<<<egrid, 512, 0, stream>>>(label, vertex, chunk, table,
                                           cntPart, zsumPart, C, H, W, HW, GX);

    dim3 hgrid(H, B);
    size_t hsm = (size_t)(C * W / 2) * 4 + (size_t)C * 4 * 8;
    hist_kernel<<<hgrid, 256, hsm, stream>>>(chunk, table, keys, C, H, W, GX);

    finalize_kernel<<<1, 512, 0, stream>>>(keys, cntPart, zsumPart, extents,
                                           meta, (float*)d_out, B, C, W, GX);
}